// Round 18
// baseline (147.074 us; speedup 1.0000x reference)
//
#include <hip/hip_runtime.h>

#define GRID_D 64
#define NN (GRID_D * GRID_D)   // 4096 nodes per image
#define H 64
#define C_IN 12
#define B_SZ 128
#define LN_EPS 1e-5f

typedef _Float16 f16x8 __attribute__((ext_vector_type(8)));
typedef _Float16 f16x4 __attribute__((ext_vector_type(4)));
typedef float    f32x4 __attribute__((ext_vector_type(4)));

#define AS1 __attribute__((address_space(1)))
#define AS3 __attribute__((address_space(3)))

__device__ __forceinline__ int pmod(int a, int m) { int r = a % m; return r < 0 ? r + m : r; }

// ---------------------------------------------------------------------------
// Kernel 1: input projection  h0[b,n,j] = sum_c x[b,c,n]*w_in[c,j] + b_in[j]
// Blocks 0..95 additionally transpose Ws/Wn to f16 (folded k_prep).
// ---------------------------------------------------------------------------
__global__ __launch_bounds__(256) void k_inproj(
    const float* __restrict__ x, const float* __restrict__ w_in,
    const float* __restrict__ b_in, _Float16* __restrict__ h,
    const float* __restrict__ ws_, const float* __restrict__ wn_,
    _Float16* __restrict__ wt)
{
    int bid = blockIdx.x;            // b*64 + r
    int b = bid >> 6, r = bid & 63;
    int tid = threadIdx.x;

    // folded weight prep: wt[l][g][j][k] = W[l,g][k][j]
    int pi = bid * 256 + tid;
    if (pi < 3 * 2 * 4096) {
        int l = pi >> 13, g = (pi >> 12) & 1, j = (pi >> 6) & 63, k = pi & 63;
        const float* W = (g ? wn_ : ws_) + l * 4096;
        wt[pi] = (_Float16)W[k * 64 + j];
    }

    __shared__ float xs[C_IN][GRID_D];
    __shared__ float ws[C_IN][H];
    const float* xb = x + (size_t)b * C_IN * NN + (size_t)r * GRID_D;
    for (int idx = tid; idx < C_IN * GRID_D; idx += 256) {
        int c = idx >> 6, n = idx & 63;
        xs[c][n] = xb[(size_t)c * NN + n];
        ws[c][n] = w_in[idx];
    }
    __syncthreads();
    int n = tid >> 2;                // node 0..63
    int j0 = (tid & 3) * 16;         // 16-feat group
    float acc[16];
    #pragma unroll
    for (int t = 0; t < 16; ++t) acc[t] = b_in[j0 + t];
    #pragma unroll
    for (int c = 0; c < C_IN; ++c) {
        float xv = xs[c][n];
        #pragma unroll
        for (int t = 0; t < 16; ++t) acc[t] += xv * ws[c][j0 + t];
    }
    _Float16* hp = h + (size_t)(b * NN + r * GRID_D + n) * H + j0;
    f16x8 o0, o1;
    #pragma unroll
    for (int t = 0; t < 8; ++t) { o0[t] = (_Float16)acc[t]; o1[t] = (_Float16)acc[8 + t]; }
    *(f16x8*)hp = o0;
    *(f16x8*)(hp + 8) = o1;
}

// stage one grid row (64 nodes x 64 f16 = 8KB) into a ring slot; linear dest,
// pre-swizzled per-lane global source (rule 21). 8 waves cover the row.
__device__ __forceinline__ void stage_row(
    const _Float16* hb, int grow, _Float16* slot, int wv, int ln)
{
    const _Float16* src = hb
        + (((size_t)(grow * GRID_D + wv * 8 + (ln >> 3))) << 6)
        + (((ln & 7) ^ (ln >> 3)) << 3);
    _Float16* dst = slot + wv * 512;
    __builtin_amdgcn_global_load_lds((const AS1 void*)src, (AS3 void*)dst, 16, 0, 0);
}

// ---------------------------------------------------------------------------
// Kernel 2: FUSED layers 1+2 (h0 -> h2 global). Block = 512 thr (8 waves)
// owns 16 output rows of one image; grid 512 = 2 blocks/CU (16 waves/CU,
// two independent barrier domains — the R12-k_fused2 proven shape,
// ~25us/layer). grpA (waves 0-3): L1 ring0->ring1. grpB (waves 4-7): L2
// ring1 -> h2 GLOBAL (plain layout). Step s (0..21): stage h0 row p=r0-2+s;
// grpA computes p-2; grpB computes p-4. Mod-4 rings, writer/reader disjoint.
// Weights pinned (64 VGPR); launch_bounds (512,2) cap 256 — caps <=128
// demote the pins (R11/12/15).
// ---------------------------------------------------------------------------
__global__ __launch_bounds__(512, 2) void k_fusedA(
    const _Float16* __restrict__ h0, _Float16* __restrict__ h2out,
    const _Float16* __restrict__ wtb,      // layers 0,1: [2][2][64][64]
    const float* __restrict__ cb, const float* __restrict__ lg,
    const float* __restrict__ lb)
{
    __shared__ _Float16 ring0[4 * 4096];   // h0, 32 KB
    __shared__ _Float16 ring1[4 * 4096];   // h1, 32 KB
    __shared__ float    pl[384];           // L1 params | L2 params

    int tid = threadIdx.x, ln = tid & 63, wv = tid >> 6;
    int bid = blockIdx.x;
    int img = bid >> 2, chunk = bid & 3;
    int r0 = chunk << 4;                   // 16 owned output rows
    const _Float16* hb = h0 + ((size_t)img << 18);
    _Float16*       ho = h2out + ((size_t)img << 18);

    int grp = wv >> 2;                     // 0 = L1, 1 = L2
    int ct  = wv & 3;
    int lrow = ln & 15, kgrp = ln >> 4, kq = kgrp * 4;
    int col = ct * 16 + lrow;
    int cs = lrow & 7;
    bool cl = (col > 0), cr = (col < 63);

    // ---- weights (layer grp): 16 frags = 64 VGPR, pinned ----
    const _Float16* wg = wtb + grp * 8192;
    f16x8 wsf[2][4], wnf[2][4];
    #pragma unroll
    for (int ks = 0; ks < 2; ++ks) {
        int k0 = ks * 32 + kq * 2;
        #pragma unroll
        for (int ft = 0; ft < 4; ++ft) {
            int j = ft * 16 + lrow;
            wsf[ks][ft] = *(const f16x8*)(wg + (j << 6) + k0);
            wnf[ks][ft] = *(const f16x8*)(wg + ((64 + j) << 6) + k0);
        }
    }
    #pragma unroll
    for (int ks = 0; ks < 2; ++ks)
        #pragma unroll
        for (int ft = 0; ft < 4; ++ft)
            asm volatile("" : "+v"(wsf[ks][ft]), "+v"(wnf[ks][ft]));

    // ---- params ----
    if (tid < 384) {
        int l = tid / 192, rr = tid % 192;
        pl[tid] = (rr < 64) ? cb[l * 64 + rr]
                : (rr < 128) ? lg[l * 64 + rr - 64] : lb[l * 64 + rr - 128];
    }
    __syncthreads();

    const float* myp = pl + grp * 192;

    int lo0 = (r0 - 2 < 0) ? 0 : r0 - 2;
    int hi0 = (r0 + 17 > 63) ? 63 : r0 + 17;
    int loC = grp ? r0 : ((r0 - 1 < 0) ? 0 : r0 - 1);
    int hiC = grp ? (r0 + 15) : ((r0 + 16 > 63) ? 63 : r0 + 16);
    const _Float16* rin = grp ? ring1 : ring0;

    #pragma unroll 1
    for (int s = 0; s <= 21; ++s) {
        int p = r0 - 2 + s;
        if (p >= lo0 && p <= hi0)
            stage_row(hb, p, ring0 + ((p & 3) << 12), wv, ln);

        int q = p - 2 - 2 * grp;               // my row this step
        if (q >= loC && q <= hiC) {
            _Float16 hinv = (_Float16)(1.0f / (float)((q > 0) + (q < 63) + cl + cr));
            f16x8 z = {};
            const _Float16* rc = rin + ((q & 3) << 12);
            const _Float16* ru = rin + (((q - 1) & 3) << 12);
            const _Float16* rd = rin + (((q + 1) & 3) << 12);

            f32x4 acc[4];
            #pragma unroll
            for (int ft = 0; ft < 4; ++ft) acc[ft] = (f32x4){0.f, 0.f, 0.f, 0.f};

            __builtin_amdgcn_s_setprio(1);
            #pragma unroll
            for (int ks = 0; ks < 2; ++ks) {
                int sl = ((ks * 4 + kgrp) ^ cs) << 3;
                f16x8 a = *(const f16x8*)(rc + (col << 6) + sl);
                #pragma unroll
                for (int ft = 0; ft < 4; ++ft)
                    acc[ft] = __builtin_amdgcn_mfma_f32_16x16x32_f16(wsf[ks][ft], a, acc[ft], 0, 0, 0);
            }
            #pragma unroll
            for (int ks = 0; ks < 2; ++ks) {
                int c8 = ks * 4 + kgrp;
                int sl = (c8 ^ cs) << 3;
                f16x8 u = (q > 0)  ? *(const f16x8*)(ru + (col << 6) + sl) : z;
                f16x8 d = (q < 63) ? *(const f16x8*)(rd + (col << 6) + sl) : z;
                int cm = col - cl;
                f16x8 lv = *(const f16x8*)(rc + (cm << 6) + ((c8 ^ (cm & 7)) << 3));
                if (!cl) lv = z;
                int cp = col + cr;
                f16x8 rv = *(const f16x8*)(rc + (cp << 6) + ((c8 ^ (cp & 7)) << 3));
                if (!cr) rv = z;
                f16x8 sm = (lv + rv) + (u + d);
                f16x8 g;
                #pragma unroll
                for (int e = 0; e < 8; ++e) g[e] = sm[e] * hinv;
                #pragma unroll
                for (int ft = 0; ft < 4; ++ft)
                    acc[ft] = __builtin_amdgcn_mfma_f32_16x16x32_f16(wnf[ks][ft], g, acc[ft], 0, 0, 0);
            }
            __builtin_amdgcn_s_setprio(0);

            float s1 = 0.f, s2 = 0.f;
            #pragma unroll
            for (int ft = 0; ft < 4; ++ft) {
                f32x4 qv = *(const f32x4*)&myp[ft * 16 + kq];
                acc[ft] += qv;
                #pragma unroll
                for (int t = 0; t < 4; ++t) { float xv = acc[ft][t]; s1 += xv; s2 += xv * xv; }
            }
            s1 += __shfl_xor(s1, 16); s1 += __shfl_xor(s1, 32);
            s2 += __shfl_xor(s2, 16); s2 += __shfl_xor(s2, 32);
            float mu   = s1 * (1.0f / H);
            float var  = s2 * (1.0f / H) - mu * mu;
            float rstd = rsqrtf(var + LN_EPS);

            const _Float16* res = rc + (col << 6);
            if (grp == 0) {
                _Float16* outp = ring1 + ((q & 3) << 12) + (col << 6);
                #pragma unroll
                for (int ft = 0; ft < 4; ++ft) {
                    f32x4 lgq = *(const f32x4*)&myp[64 + ft * 16 + kq];
                    f32x4 lbq = *(const f32x4*)&myp[128 + ft * 16 + kq];
                    int slot = (ft * 2 + (kgrp >> 1)) ^ cs;
                    f16x4 rq = *(const f16x4*)(res + (slot << 3) + (kgrp & 1) * 4);
                    f16x4 oq;
                    #pragma unroll
                    for (int t = 0; t < 4; ++t) {
                        float o = (float)rq[t]
                                + fmaxf((acc[ft][t] - mu) * rstd * lgq[t] + lbq[t], 0.f);
                        oq[t] = (_Float16)o;
                    }
                    *(f16x4*)(outp + (slot << 3) + (kgrp & 1) * 4) = oq;
                }
            } else {
                _Float16* outp = ho + (((size_t)(q * GRID_D + col)) << 6);
                #pragma unroll
                for (int ft = 0; ft < 4; ++ft) {
                    f32x4 lgq = *(const f32x4*)&myp[64 + ft * 16 + kq];
                    f32x4 lbq = *(const f32x4*)&myp[128 + ft * 16 + kq];
                    int slot = (ft * 2 + (kgrp >> 1)) ^ cs;
                    f16x4 rq = *(const f16x4*)(res + (slot << 3) + (kgrp & 1) * 4);
                    f16x4 oq;
                    #pragma unroll
                    for (int t = 0; t < 4; ++t) {
                        float o = (float)rq[t]
                                + fmaxf((acc[ft][t] - mu) * rstd * lgq[t] + lbq[t], 0.f);
                        oq[t] = (_Float16)o;
                    }
                    *(f16x4*)(outp + ft * 16 + kq) = oq;   // plain layout
                }
            }
        }
        __syncthreads();
    }
}

// ---------------------------------------------------------------------------
// Kernel 3: layer 3 + head (h2 -> logits). Block = 512 thr (8 waves) owns 16
// output rows; grid 512 = 2 blocks/CU. Waves: rp = wv>>2 (row of pair),
// ct = wv&3 (col tile). 6-slot h2 ring staged 2 rows/step. Step s (0..9):
// stage rows P=r0-1+2s, P+1; compute rows qb=r0-4+2s (+rp). Writer slots
// P..P+1 vs reader rows P-4..P-1 — mod-6 disjoint; inputs staged >=1 step
// earlier. Weights pinned.
// ---------------------------------------------------------------------------
__global__ __launch_bounds__(512, 2) void k_fusedB(
    const _Float16* __restrict__ h2, float* __restrict__ logits,
    const _Float16* __restrict__ wtb,      // layer 2 weights [2][64][64]
    const float* __restrict__ cb, const float* __restrict__ lg,
    const float* __restrict__ lb,
    const float* __restrict__ w_head, const float* __restrict__ b_head)
{
    __shared__ _Float16 ring[6 * 4096];    // h2, 48 KB, mod-6
    __shared__ float    pl[256];           // L3 params | w_head

    int tid = threadIdx.x, ln = tid & 63, wv = tid >> 6;
    int bid = blockIdx.x;
    int img = bid >> 2, chunk = bid & 3;
    int r0 = chunk << 4;
    const _Float16* hb = h2 + ((size_t)img << 18);

    int rp = wv >> 2;                      // row of the pair
    int ct = wv & 3;
    int lrow = ln & 15, kgrp = ln >> 4, kq = kgrp * 4;
    int col = ct * 16 + lrow;
    int cs = lrow & 7;
    bool cl = (col > 0), cr = (col < 63);

    // ---- weights (layer 3): 16 frags = 64 VGPR, pinned ----
    f16x8 wsf[2][4], wnf[2][4];
    #pragma unroll
    for (int ks = 0; ks < 2; ++ks) {
        int k0 = ks * 32 + kq * 2;
        #pragma unroll
        for (int ft = 0; ft < 4; ++ft) {
            int j = ft * 16 + lrow;
            wsf[ks][ft] = *(const f16x8*)(wtb + (j << 6) + k0);
            wnf[ks][ft] = *(const f16x8*)(wtb + ((64 + j) << 6) + k0);
        }
    }
    #pragma unroll
    for (int ks = 0; ks < 2; ++ks)
        #pragma unroll
        for (int ft = 0; ft < 4; ++ft)
            asm volatile("" : "+v"(wsf[ks][ft]), "+v"(wnf[ks][ft]));

    if (tid < 192) {
        pl[tid] = (tid < 64) ? cb[tid] : (tid < 128) ? lg[tid - 64] : lb[tid - 128];
    } else if (tid < 256) {
        pl[tid] = w_head[tid - 192];
    }
    __syncthreads();

    float bh = b_head[0];
    int loS = (r0 - 1 < 0) ? 0 : r0 - 1;
    int hiS = (r0 + 16 > 63) ? 63 : r0 + 16;

    // slot trackers (row x <-> slot x mod 6), advanced +2 per step
    int stA = pmod(r0 - 1, 6), stB = pmod(r0, 6);
    int s0 = pmod(r0 - 5, 6), s1_ = pmod(r0 - 4, 6);
    int s2_ = pmod(r0 - 3, 6), s3 = pmod(r0 - 2, 6);
    int qb = r0 - 4;

    #pragma unroll 1
    for (int s = 0; s <= 9; ++s) {
        int P = r0 - 1 + 2 * s;
        if (P >= loS && P <= hiS)
            stage_row(hb, P, ring + (stA << 12), wv, ln);
        if (P + 1 >= loS && P + 1 <= hiS)
            stage_row(hb, P + 1, ring + (stB << 12), wv, ln);

        int q = qb + rp;
        if (q >= r0 && q <= r0 + 15) {
            int sA = rp ? s1_ : s0;            // row q-1
            int sB = rp ? s2_ : s1_;           // row q
            int sC = rp ? s3 : s2_;            // row q+1
            _Float16 hinv = (_Float16)(1.0f / (float)((q > 0) + (q < 63) + cl + cr));
            f16x8 z = {};
            const _Float16* rc = ring + (sB << 12);
            const _Float16* ru = ring + (sA << 12);
            const _Float16* rd = ring + (sC << 12);

            f32x4 acc[4];
            #pragma unroll
            for (int ft = 0; ft < 4; ++ft) acc[ft] = (f32x4){0.f, 0.f, 0.f, 0.f};

            __builtin_amdgcn_s_setprio(1);
            #pragma unroll
            for (int ks = 0; ks < 2; ++ks) {
                int sl = ((ks * 4 + kgrp) ^ cs) << 3;
                f16x8 a = *(const f16x8*)(rc + (col << 6) + sl);
                #pragma unroll
                for (int ft = 0; ft < 4; ++ft)
                    acc[ft] = __builtin_amdgcn_mfma_f32_16x16x32_f16(wsf[ks][ft], a, acc[ft], 0, 0, 0);
            }
            #pragma unroll
            for (int ks = 0; ks < 2; ++ks) {
                int c8 = ks * 4 + kgrp;
                int sl = (c8 ^ cs) << 3;
                f16x8 u = (q > 0)  ? *(const f16x8*)(ru + (col << 6) + sl) : z;
                f16x8 d = (q < 63) ? *(const f16x8*)(rd + (col << 6) + sl) : z;
                int cm = col - cl;
                f16x8 lv = *(const f16x8*)(rc + (cm << 6) + ((c8 ^ (cm & 7)) << 3));
                if (!cl) lv = z;
                int cp = col + cr;
                f16x8 rv = *(const f16x8*)(rc + (cp << 6) + ((c8 ^ (cp & 7)) << 3));
                if (!cr) rv = z;
                f16x8 sm = (lv + rv) + (u + d);
                f16x8 g;
                #pragma unroll
                for (int e = 0; e < 8; ++e) g[e] = sm[e] * hinv;
                #pragma unroll
                for (int ft = 0; ft < 4; ++ft)
                    acc[ft] = __builtin_amdgcn_mfma_f32_16x16x32_f16(wnf[ks][ft], g, acc[ft], 0, 0, 0);
            }
            __builtin_amdgcn_s_setprio(0);

            float t1 = 0.f, t2 = 0.f;
            #pragma unroll
            for (int ft = 0; ft < 4; ++ft) {
                f32x4 qv = *(const f32x4*)&pl[ft * 16 + kq];
                acc[ft] += qv;
                #pragma unroll
                for (int t = 0; t < 4; ++t) { float xv = acc[ft][t]; t1 += xv; t2 += xv * xv; }
            }
            t1 += __shfl_xor(t1, 16); t1 += __shfl_xor(t1, 32);
            t2 += __shfl_xor(t2, 16); t2 += __shfl_xor(t2, 32);
            float mu   = t1 * (1.0f / H);
            float var  = t2 * (1.0f / H) - mu * mu;
            float rstd = rsqrtf(var + LN_EPS);

            const _Float16* res = rc + (col << 6);
            float part = 0.f;
            #pragma unroll
            for (int ft = 0; ft < 4; ++ft) {
                f32x4 lgq = *(const f32x4*)&pl[64 + ft * 16 + kq];
                f32x4 lbq = *(const f32x4*)&pl[128 + ft * 16 + kq];
                f32x4 whq = *(const f32x4*)&pl[192 + ft * 16 + kq];
                int slot = (ft * 2 + (kgrp >> 1)) ^ cs;
                f16x4 rq = *(const f16x4*)(res + (slot << 3) + (kgrp & 1) * 4);
                #pragma unroll
                for (int t = 0; t < 4; ++t) {
                    float o = (float)rq[t]
                            + fmaxf((acc[ft][t] - mu) * rstd * lgq[t] + lbq[t], 0.f);
                    part += o * whq[t];
                }
            }
            part += __shfl_xor(part, 16);
            part += __shfl_xor(part, 32);
            if (kgrp == 0)
                logits[(size_t)img * NN + q * GRID_D + col] = part + bh;
        }

        stA += 2; if (stA >= 6) stA -= 6;
        stB += 2; if (stB >= 6) stB -= 6;
        s0  += 2; if (s0  >= 6) s0  -= 6;
        s1_ += 2; if (s1_ >= 6) s1_ -= 6;
        s2_ += 2; if (s2_ >= 6) s2_ -= 6;
        s3  += 2; if (s3  >= 6) s3  -= 6;
        qb += 2;

        __syncthreads();
    }
}

// ---------------------------------------------------------------------------
extern "C" void kernel_launch(void* const* d_in, const int* in_sizes, int n_in,
                              void* d_out, int out_size, void* d_ws, size_t ws_size,
                              hipStream_t stream) {
    const float* x      = (const float*)d_in[0];
    // d_in[1] edge_index: fixed grid 4-neighborhood -> computed as stencil, unused
    const float* w_in   = (const float*)d_in[2];
    const float* b_in   = (const float*)d_in[3];
    const float* w_self = (const float*)d_in[4];
    const float* w_neigh= (const float*)d_in[5];
    const float* conv_b = (const float*)d_in[6];
    const float* ln_g   = (const float*)d_in[7];
    const float* ln_b   = (const float*)d_in[8];
    const float* w_head = (const float*)d_in[9];
    const float* b_head = (const float*)d_in[10];
    float* out = (float*)d_out;

    char* base = (char*)d_ws;
    const size_t HBYTES = (size_t)B_SZ * NN * H * sizeof(_Float16);   // 64 MiB
    _Float16* h_a = (_Float16*)base;                                  // h0
    _Float16* h_c = (_Float16*)(base + HBYTES);                       // h2
    _Float16* wtb = (_Float16*)(base + 2 * HBYTES);                   // 48 KiB

    k_inproj<<<B_SZ * GRID_D, 256, 0, stream>>>(
        x, w_in, b_in, h_a, w_self, w_neigh, wtb);
    k_fusedA<<<B_SZ * 4, 512, 0, stream>>>(
        h_a, h_c, wtb, conv_b, ln_g, ln_b);
    k_fusedB<<<B_SZ * 4, 512, 0, stream>>>(
        h_c, out, wtb + 16384, conv_b + 2 * H, ln_g + 2 * H, ln_b + 2 * H,
        w_head, b_head);
}

// Round 19
// 111.708 us; speedup vs baseline: 1.3166x; 1.3166x over previous
//
#include <hip/hip_runtime.h>

#define GRID_D 64
#define NN (GRID_D * GRID_D)   // 4096 nodes per image
#define H 64
#define C_IN 12
#define B_SZ 128
#define LN_EPS 1e-5f

typedef _Float16 f16x8 __attribute__((ext_vector_type(8)));
typedef _Float16 f16x4 __attribute__((ext_vector_type(4)));
typedef float    f32x4 __attribute__((ext_vector_type(4)));

#define AS1 __attribute__((address_space(1)))
#define AS3 __attribute__((address_space(3)))

__device__ __forceinline__ int pmod(int a, int m) { int r = a % m; return r < 0 ? r + m : r; }

// ---------------------------------------------------------------------------
// Kernel 1: input projection  h0[b,n,j] = sum_c x[b,c,n]*w_in[c,j] + b_in[j]
// Blocks 0..95 additionally transpose Ws/Wn to f16 (folded k_prep).
// ---------------------------------------------------------------------------
__global__ __launch_bounds__(256) void k_inproj(
    const float* __restrict__ x, const float* __restrict__ w_in,
    const float* __restrict__ b_in, _Float16* __restrict__ h,
    const float* __restrict__ ws_, const float* __restrict__ wn_,
    _Float16* __restrict__ wt)
{
    int bid = blockIdx.x;            // b*64 + r
    int b = bid >> 6, r = bid & 63;
    int tid = threadIdx.x;

    // folded weight prep: wt[l][g][j][k] = W[l,g][k][j]
    int pi = bid * 256 + tid;
    if (pi < 3 * 2 * 4096) {
        int l = pi >> 13, g = (pi >> 12) & 1, j = (pi >> 6) & 63, k = pi & 63;
        const float* W = (g ? wn_ : ws_) + l * 4096;
        wt[pi] = (_Float16)W[k * 64 + j];
    }

    __shared__ float xs[C_IN][GRID_D];
    __shared__ float ws[C_IN][H];
    const float* xb = x + (size_t)b * C_IN * NN + (size_t)r * GRID_D;
    for (int idx = tid; idx < C_IN * GRID_D; idx += 256) {
        int c = idx >> 6, n = idx & 63;
        xs[c][n] = xb[(size_t)c * NN + n];
        ws[c][n] = w_in[idx];
    }
    __syncthreads();
    int n = tid >> 2;                // node 0..63
    int j0 = (tid & 3) * 16;         // 16-feat group
    float acc[16];
    #pragma unroll
    for (int t = 0; t < 16; ++t) acc[t] = b_in[j0 + t];
    #pragma unroll
    for (int c = 0; c < C_IN; ++c) {
        float xv = xs[c][n];
        #pragma unroll
        for (int t = 0; t < 16; ++t) acc[t] += xv * ws[c][j0 + t];
    }
    _Float16* hp = h + (size_t)(b * NN + r * GRID_D + n) * H + j0;
    f16x8 o0, o1;
    #pragma unroll
    for (int t = 0; t < 8; ++t) { o0[t] = (_Float16)acc[t]; o1[t] = (_Float16)acc[8 + t]; }
    *(f16x8*)hp = o0;
    *(f16x8*)(hp + 8) = o1;
}

// stage one grid row (64 nodes x 64 f16 = 8KB) into a ring slot; linear dest,
// pre-swizzled per-lane global source (rule 21). Waves 0..7, one gload each.
__device__ __forceinline__ void stage_row(
    const _Float16* hb, int grow, _Float16* slot, int wv, int ln)
{
    const _Float16* src = hb
        + (((size_t)(grow * GRID_D + wv * 8 + (ln >> 3))) << 6)
        + (((ln & 7) ^ (ln >> 3)) << 3);
    _Float16* dst = slot + wv * 512;
    __builtin_amdgcn_global_load_lds((const AS1 void*)src, (AS3 void*)dst, 16, 0, 0);
}

// ---------------------------------------------------------------------------
// Kernel 2: FUSED 3 layers + head (R16 structure + T4 counted-vmcnt barrier).
// Block = 768 thr (12 waves) owns 32 output rows of one image (grid 256 =
// 1 block/CU). Step s (0..40): stage h0 row S = r0-2+s into ring0 (5 slots,
// mod-5) — every row staged exactly TWO steps before its first read. Barrier
// = inline `s_waitcnt vmcnt(1) lgkmcnt(0); s_barrier`: the newest stage load
// stays in flight across the barrier (T4 — never drain to 0 mid-loop);
// rows become non-newest (thus complete) one step before they're read.
// No-stage steps use vmcnt(0) (block-uniform condition) to avoid the
// sole-outstanding-load hazard. grp0 (waves 0-3): h1 row p0-2 (ring0->ring1);
// grp1: h2 p0-4 (ring1->ring2); grp2: h3+head p0-6 -> logits (p0 = r0-3+s).
// ring1/ring2 mod-4 as before (writer/reader disjoint). Weights: 16
// f16x8/lane in VGPRs, pinned — stable ONLY at block=768 + min-waves=3.
// ---------------------------------------------------------------------------
__global__ __launch_bounds__(768, 3) void k_fused(
    const _Float16* __restrict__ h0, float* __restrict__ logits,
    const _Float16* __restrict__ wtb,      // [3][2][64][64] transposed f16
    const float* __restrict__ cb, const float* __restrict__ lg,
    const float* __restrict__ lb,
    const float* __restrict__ w_head, const float* __restrict__ b_head)
{
    __shared__ _Float16 ring0[5 * 4096];   // h0, 40 KB, mod-5
    __shared__ _Float16 ring1[4 * 4096];   // h1, 32 KB, mod-4
    __shared__ _Float16 ring2[4 * 4096];   // h2, 32 KB, mod-4
    __shared__ float    pl[640];           // cb|lg|lb per layer (3x192) + wh(64)

    int tid = threadIdx.x, ln = tid & 63, wv = tid >> 6;
    int bid = blockIdx.x;
    int img = bid >> 1, chunk = bid & 1;
    int r0 = chunk << 5;                   // 32 output rows
    const _Float16* hb = h0 + ((size_t)img << 18);

    int grp = wv >> 2;                     // 0,1,2 = layer-1,2,3
    int ct  = wv & 3;                      // col tile
    int lrow = ln & 15, kgrp = ln >> 4;
    int col = ct * 16 + lrow;
    int cs = col & 7;                      // == lrow & 7
    int kq = kgrp * 4;
    bool cl = (col > 0), cr = (col < 63);

    // ---- weights for my group's layer: 16 frags = 64 VGPR, pinned ----
    const _Float16* wg = wtb + grp * 8192;
    f16x8 wsf[2][4], wnf[2][4];
    #pragma unroll
    for (int ks = 0; ks < 2; ++ks) {
        int k0 = ks * 32 + kq * 2;         // ks*32 + kgrp*8
        #pragma unroll
        for (int ft = 0; ft < 4; ++ft) {
            int j = ft * 16 + lrow;
            wsf[ks][ft] = *(const f16x8*)(wg + (j << 6) + k0);
            wnf[ks][ft] = *(const f16x8*)(wg + ((64 + j) << 6) + k0);
        }
    }
    #pragma unroll
    for (int ks = 0; ks < 2; ++ks)
        #pragma unroll
        for (int ft = 0; ft < 4; ++ft)
            asm volatile("" : "+v"(wsf[ks][ft]), "+v"(wnf[ks][ft]));

    // ---- params to LDS ----
    if (tid < 576) {
        int l = tid / 192, r = tid % 192;
        pl[tid] = (r < 64) ? cb[l * 64 + r]
                : (r < 128) ? lg[l * 64 + r - 64] : lb[l * 64 + r - 128];
    } else if (tid < 640) {
        pl[tid] = w_head[tid - 576];
    }

    const float* myp = pl + grp * 192;
    float bh = b_head[0];

    // stage/compute validity ranges (clipped to image)
    int lo0 = (r0 - 3 < 0) ? 0 : r0 - 3, hi0 = (r0 + 34 > 63) ? 63 : r0 + 34;
    int loC, hiC;
    if (grp == 0)      { loC = (r0 - 2 < 0) ? 0 : r0 - 2; hiC = (r0 + 33 > 63) ? 63 : r0 + 33; }
    else if (grp == 1) { loC = (r0 - 1 < 0) ? 0 : r0 - 1; hiC = (r0 + 32 > 63) ? 63 : r0 + 32; }
    else               { loC = r0;                         hiC = r0 + 31; }

    const _Float16* rin = (grp == 0) ? ring0 : (grp == 1) ? ring1 : ring2;
    _Float16* rout      = (grp == 0) ? ring1 : ring2;     // grp2: unused

    // grp0 ring0 slot trackers (mod 5), rows pr-1, pr, pr+1 at pr = r0-5+s
    int a0 = pmod(r0 - 6, 5), a1 = pmod(r0 - 5, 5), a2 = pmod(r0 - 4, 5);
    int stS = pmod(r0 - 2, 5);             // staging slot for S = r0-2+s

    #pragma unroll 1
    for (int s = 0; s <= 40; ++s) {
        int S = r0 - 2 + s;                // staged row (2-step lead)
        bool do_stage = (S >= lo0 && S <= hi0);
        if (wv < 8) {
            if (s == 0 && r0 - 3 >= 0)     // prologue: also stage row r0-3
                stage_row(hb, r0 - 3, ring0 + (pmod(r0 - 3, 5) << 12), wv, ln);
            if (do_stage)
                stage_row(hb, S, ring0 + (stS << 12), wv, ln);
        }

        int p0 = r0 - 3 + s;
        int pr = p0 - 2 * grp - 2;                     // my group's row this step
        if (pr >= loC && pr <= hiC) {
            const _Float16 *rc, *ru, *rd;
            if (grp == 0) {
                rc = ring0 + (a1 << 12);
                ru = ring0 + (a0 << 12);
                rd = ring0 + (a2 << 12);
            } else {
                rc = rin + ((pr & 3) << 12);
                ru = rin + (((pr - 1) & 3) << 12);
                rd = rin + (((pr + 1) & 3) << 12);
            }
            _Float16 hinv = (_Float16)(1.0f / (float)((pr > 0) + (pr < 63) + cl + cr));

            f32x4 acc[4];
            #pragma unroll
            for (int ft = 0; ft < 4; ++ft) acc[ft] = (f32x4){0.f, 0.f, 0.f, 0.f};

            // phase 1: Ws^T @ self^T
            __builtin_amdgcn_s_setprio(1);
            #pragma unroll
            for (int ks = 0; ks < 2; ++ks) {
                int sl = ((ks * 4 + kgrp) ^ cs) << 3;
                f16x8 a = *(const f16x8*)(rc + (col << 6) + sl);
                #pragma unroll
                for (int ft = 0; ft < 4; ++ft)
                    acc[ft] = __builtin_amdgcn_mfma_f32_16x16x32_f16(wsf[ks][ft], a, acc[ft], 0, 0, 0);
            }

            // phase 2: Wn^T @ agg^T
            #pragma unroll
            for (int ks = 0; ks < 2; ++ks) {
                int c8 = ks * 4 + kgrp;
                int sl = (c8 ^ cs) << 3;
                f16x8 z = {};
                f16x8 u = (pr > 0)  ? *(const f16x8*)(ru + (col << 6) + sl) : z;
                f16x8 d = (pr < 63) ? *(const f16x8*)(rd + (col << 6) + sl) : z;
                int cm = col - cl;
                f16x8 lv = *(const f16x8*)(rc + (cm << 6) + ((c8 ^ (cm & 7)) << 3));
                if (!cl) lv = z;
                int cp = col + cr;
                f16x8 rv = *(const f16x8*)(rc + (cp << 6) + ((c8 ^ (cp & 7)) << 3));
                if (!cr) rv = z;
                f16x8 sm = (lv + rv) + (u + d);
                f16x8 g;
                #pragma unroll
                for (int e = 0; e < 8; ++e) g[e] = sm[e] * hinv;
                #pragma unroll
                for (int ft = 0; ft < 4; ++ft)
                    acc[ft] = __builtin_amdgcn_mfma_f32_16x16x32_f16(wnf[ks][ft], g, acc[ft], 0, 0, 0);
            }
            __builtin_amdgcn_s_setprio(0);

            // epilogue: +bias, LN, residual+ReLU -> ring or logits
            float s1 = 0.f, s2 = 0.f;
            #pragma unroll
            for (int ft = 0; ft < 4; ++ft) {
                f32x4 q = *(const f32x4*)&myp[ft * 16 + kq];
                acc[ft] += q;
                #pragma unroll
                for (int t = 0; t < 4; ++t) { float xv = acc[ft][t]; s1 += xv; s2 += xv * xv; }
            }
            s1 += __shfl_xor(s1, 16); s1 += __shfl_xor(s1, 32);
            s2 += __shfl_xor(s2, 16); s2 += __shfl_xor(s2, 32);
            float mu   = s1 * (1.0f / H);
            float var  = s2 * (1.0f / H) - mu * mu;
            float rstd = rsqrtf(var + LN_EPS);

            const _Float16* res = rc + (col << 6);
            if (grp < 2) {
                _Float16* outp = rout + ((pr & 3) << 12) + (col << 6);
                #pragma unroll
                for (int ft = 0; ft < 4; ++ft) {
                    f32x4 lgq = *(const f32x4*)&myp[64 + ft * 16 + kq];
                    f32x4 lbq = *(const f32x4*)&myp[128 + ft * 16 + kq];
                    int slot = (ft * 2 + (kgrp >> 1)) ^ cs;
                    f16x4 rq = *(const f16x4*)(res + (slot << 3) + (kgrp & 1) * 4);
                    f16x4 oq;
                    #pragma unroll
                    for (int t = 0; t < 4; ++t) {
                        float o = (float)rq[t]
                                + fmaxf((acc[ft][t] - mu) * rstd * lgq[t] + lbq[t], 0.f);
                        oq[t] = (_Float16)o;
                    }
                    *(f16x4*)(outp + (slot << 3) + (kgrp & 1) * 4) = oq;
                }
            } else {
                float part = 0.f;
                #pragma unroll
                for (int ft = 0; ft < 4; ++ft) {
                    f32x4 lgq = *(const f32x4*)&myp[64 + ft * 16 + kq];
                    f32x4 lbq = *(const f32x4*)&myp[128 + ft * 16 + kq];
                    f32x4 whq = *(const f32x4*)&pl[576 + ft * 16 + kq];
                    int slot = (ft * 2 + (kgrp >> 1)) ^ cs;
                    f16x4 rq = *(const f16x4*)(res + (slot << 3) + (kgrp & 1) * 4);
                    #pragma unroll
                    for (int t = 0; t < 4; ++t) {
                        float o = (float)rq[t]
                                + fmaxf((acc[ft][t] - mu) * rstd * lgq[t] + lbq[t], 0.f);
                        part += o * whq[t];
                    }
                }
                part += __shfl_xor(part, 16);
                part += __shfl_xor(part, 32);
                if (kgrp == 0)
                    logits[(size_t)img * NN + pr * GRID_D + col] = part + bh;
            }
        }

        // advance trackers
        a0 += 1; if (a0 >= 5) a0 -= 5;
        a1 += 1; if (a1 >= 5) a1 -= 5;
        a2 += 1; if (a2 >= 5) a2 -= 5;
        stS += 1; if (stS >= 5) stS -= 5;

        // T4 barrier: newest stage load may stay in flight (it is read 2
        // steps from now); older loads + all LDS ops must be complete.
        // do_stage is block-uniform.
        if (do_stage)
            asm volatile("s_waitcnt vmcnt(1) lgkmcnt(0)\n\ts_barrier" ::: "memory");
        else
            asm volatile("s_waitcnt vmcnt(0) lgkmcnt(0)\n\ts_barrier" ::: "memory");
    }
}

// ---------------------------------------------------------------------------
extern "C" void kernel_launch(void* const* d_in, const int* in_sizes, int n_in,
                              void* d_out, int out_size, void* d_ws, size_t ws_size,
                              hipStream_t stream) {
    const float* x      = (const float*)d_in[0];
    // d_in[1] edge_index: fixed grid 4-neighborhood -> computed as stencil, unused
    const float* w_in   = (const float*)d_in[2];
    const float* b_in   = (const float*)d_in[3];
    const float* w_self = (const float*)d_in[4];
    const float* w_neigh= (const float*)d_in[5];
    const float* conv_b = (const float*)d_in[6];
    const float* ln_g   = (const float*)d_in[7];
    const float* ln_b   = (const float*)d_in[8];
    const float* w_head = (const float*)d_in[9];
    const float* b_head = (const float*)d_in[10];
    float* out = (float*)d_out;

    char* base = (char*)d_ws;
    const size_t HBYTES = (size_t)B_SZ * NN * H * sizeof(_Float16);   // 64 MiB
    _Float16* h_a = (_Float16*)base;
    _Float16* wtb = (_Float16*)(base + HBYTES);                       // 48 KiB

    k_inproj<<<B_SZ * GRID_D, 256, 0, stream>>>(
        x, w_in, b_in, h_a, w_self, w_neigh, wtb);
    k_fused<<<B_SZ * 2, 768, 0, stream>>>(
        h_a, out, wtb, conv_b, ln_g, ln_b, w_head, b_head);
}

// Round 20
// 104.347 us; speedup vs baseline: 1.4095x; 1.0706x over previous
//
#include <hip/hip_runtime.h>

#define GRID_D 64
#define NN (GRID_D * GRID_D)   // 4096 nodes per image
#define H 64
#define C_IN 12
#define B_SZ 128
#define LN_EPS 1e-5f

typedef _Float16 f16x8 __attribute__((ext_vector_type(8)));
typedef _Float16 f16x4 __attribute__((ext_vector_type(4)));
typedef float    f32x4 __attribute__((ext_vector_type(4)));

#define AS1 __attribute__((address_space(1)))
#define AS3 __attribute__((address_space(3)))

// ---------------------------------------------------------------------------
// Kernel 1: input projection  h0[b,n,j] = sum_c x[b,c,n]*w_in[c,j] + b_in[j]
// Blocks 0..95 additionally transpose Ws/Wn to f16 (folded k_prep).
// ---------------------------------------------------------------------------
__global__ __launch_bounds__(256) void k_inproj(
    const float* __restrict__ x, const float* __restrict__ w_in,
    const float* __restrict__ b_in, _Float16* __restrict__ h,
    const float* __restrict__ ws_, const float* __restrict__ wn_,
    _Float16* __restrict__ wt)
{
    int bid = blockIdx.x;            // b*64 + r
    int b = bid >> 6, r = bid & 63;
    int tid = threadIdx.x;

    // folded weight prep: wt[l][g][j][k] = W[l,g][k][j]
    int pi = bid * 256 + tid;
    if (pi < 3 * 2 * 4096) {
        int l = pi >> 13, g = (pi >> 12) & 1, j = (pi >> 6) & 63, k = pi & 63;
        const float* W = (g ? wn_ : ws_) + l * 4096;
        wt[pi] = (_Float16)W[k * 64 + j];
    }

    __shared__ float xs[C_IN][GRID_D];
    __shared__ float ws[C_IN][H];
    const float* xb = x + (size_t)b * C_IN * NN + (size_t)r * GRID_D;
    for (int idx = tid; idx < C_IN * GRID_D; idx += 256) {
        int c = idx >> 6, n = idx & 63;
        xs[c][n] = xb[(size_t)c * NN + n];
        ws[c][n] = w_in[idx];
    }
    __syncthreads();
    int n = tid >> 2;                // node 0..63
    int j0 = (tid & 3) * 16;         // 16-feat group
    float acc[16];
    #pragma unroll
    for (int t = 0; t < 16; ++t) acc[t] = b_in[j0 + t];
    #pragma unroll
    for (int c = 0; c < C_IN; ++c) {
        float xv = xs[c][n];
        #pragma unroll
        for (int t = 0; t < 16; ++t) acc[t] += xv * ws[c][j0 + t];
    }
    _Float16* hp = h + (size_t)(b * NN + r * GRID_D + n) * H + j0;
    f16x8 o0, o1;
    #pragma unroll
    for (int t = 0; t < 8; ++t) { o0[t] = (_Float16)acc[t]; o1[t] = (_Float16)acc[8 + t]; }
    *(f16x8*)hp = o0;
    *(f16x8*)(hp + 8) = o1;
}

// stage one grid row (64 nodes x 64 f16 = 8KB) into ring0 slot; linear dest,
// pre-swizzled per-lane global source (rule 21). Waves 0..7, one gload each.
__device__ __forceinline__ void stage_row(
    const _Float16* hb, int grow, _Float16* slot, int wv, int ln)
{
    const _Float16* src = hb
        + (((size_t)(grow * GRID_D + wv * 8 + (ln >> 3))) << 6)
        + (((ln & 7) ^ (ln >> 3)) << 3);
    _Float16* dst = slot + wv * 512;
    __builtin_amdgcn_global_load_lds((const AS1 void*)src, (AS3 void*)dst, 16, 0, 0);
}

// ---------------------------------------------------------------------------
// Kernel 2: FUSED 3 layers + head (R16 structure + VALU micro-cuts).
// Block = 768 thr (12 waves) owns 32 output rows of one image (grid 256 =
// 1 block/CU). Step s: stage h0[p0] async into ring0 (waves 0-7); waves 0-3:
// h1[p0-2] (ring0->ring1); waves 4-7: h2[p0-4] (ring1->ring2); waves 8-11:
// h3[p0-6]+head -> logits. One barrier/step; mod-4 ring slots. Weights: 16
// f16x8/lane in VGPRs, pinned — stable ONLY at block=768 + min-waves=3.
// NEW vs R16: (1) zero-slot boundary handling — OOB row-neighbors are a
// wave-uniform pointer select to an 8KB zeroed LDS row (scalar, free) and
// OOB col-neighbors a single per-lane address select, replacing ~32 value
// cndmasks/step/wave; (2) conv-bias quads hoisted to registers (pre-loop
// barrier publishes params+zbuf).
// ---------------------------------------------------------------------------
__global__ __launch_bounds__(768, 3) void k_fused(
    const _Float16* __restrict__ h0, float* __restrict__ logits,
    const _Float16* __restrict__ wtb,      // [3][2][64][64] transposed f16
    const float* __restrict__ cb, const float* __restrict__ lg,
    const float* __restrict__ lb,
    const float* __restrict__ w_head, const float* __restrict__ b_head)
{
    __shared__ _Float16 ring[3][4][4096];  // 96 KB
    __shared__ _Float16 zbuf[4096];        // 8 KB of zeros (boundary reads)
    __shared__ float    pl[640];           // cb|lg|lb per layer (3x192) + wh(64)

    int tid = threadIdx.x, ln = tid & 63, wv = tid >> 6;
    int bid = blockIdx.x;
    int img = bid >> 1, chunk = bid & 1;
    int r0 = chunk << 5;                   // 32 output rows
    const _Float16* hb = h0 + ((size_t)img << 18);

    int grp = wv >> 2;                     // 0,1,2 = layer-1,2,3
    int ct  = wv & 3;                      // col tile
    int lrow = ln & 15, kgrp = ln >> 4;
    int col = ct * 16 + lrow;
    int cs = col & 7;                      // == lrow & 7
    int kq = kgrp * 4;
    bool cl = (col > 0), cr = (col < 63);

    // ---- weights for my group's layer: 16 frags = 64 VGPR, pinned ----
    const _Float16* wg = wtb + grp * 8192;
    f16x8 wsf[2][4], wnf[2][4];
    #pragma unroll
    for (int ks = 0; ks < 2; ++ks) {
        int k0 = ks * 32 + kq * 2;         // ks*32 + kgrp*8
        #pragma unroll
        for (int ft = 0; ft < 4; ++ft) {
            int j = ft * 16 + lrow;
            wsf[ks][ft] = *(const f16x8*)(wg + (j << 6) + k0);
            wnf[ks][ft] = *(const f16x8*)(wg + ((64 + j) << 6) + k0);
        }
    }
    #pragma unroll
    for (int ks = 0; ks < 2; ++ks)
        #pragma unroll
        for (int ft = 0; ft < 4; ++ft)
            asm volatile("" : "+v"(wsf[ks][ft]), "+v"(wnf[ks][ft]));

    // ---- params + zero slot to LDS ----
    if (tid < 576) {
        int l = tid / 192, r = tid % 192;
        pl[tid] = (r < 64) ? cb[l * 64 + r]
                : (r < 128) ? lg[l * 64 + r - 64] : lb[l * 64 + r - 128];
    } else if (tid < 640) {
        pl[tid] = w_head[tid - 576];
    }
    if (tid < 512) {
        f16x8 z = {};
        *(f16x8*)&zbuf[tid * 8] = z;
    }
    __syncthreads();                       // publish params + zbuf for hoists

    const float* myp = pl + grp * 192;
    float bh = b_head[0];

    // hoisted loop-invariant conv-bias quads (4 x f32x4 = 16 VGPR)
    f32x4 cbq[4];
    #pragma unroll
    for (int ft = 0; ft < 4; ++ft) cbq[ft] = *(const f32x4*)&myp[ft * 16 + kq];

    // loop-invariant neighbor column offsets (element units)
    int colo = col << 6;
    int cmo = cl ? (((col - 1) << 6)) : 0;          // valid only when cl
    int cpo = cr ? (((col + 1) << 6)) : 0;

    // stage/compute validity ranges (clipped to image)
    int lo0 = (r0 - 3 < 0) ? 0 : r0 - 3, hi0 = (r0 + 34 > 63) ? 63 : r0 + 34;
    int loC, hiC;
    if (grp == 0)      { loC = (r0 - 2 < 0) ? 0 : r0 - 2; hiC = (r0 + 33 > 63) ? 63 : r0 + 33; }
    else if (grp == 1) { loC = (r0 - 1 < 0) ? 0 : r0 - 1; hiC = (r0 + 32 > 63) ? 63 : r0 + 32; }
    else               { loC = r0;                         hiC = r0 + 31; }

    _Float16* rin  = &ring[grp][0][0];                 // group g reads ring[g]
    _Float16* rout = (grp < 2) ? &ring[grp + 1][0][0] : nullptr;

    #pragma unroll 1
    for (int s = 0; s <= 40; ++s) {
        int p0 = r0 - 3 + s;
        if (wv < 8 && p0 >= lo0 && p0 <= hi0)
            stage_row(hb, p0, &ring[0][p0 & 3][0], wv, ln);

        int pr = p0 - 2 * grp - 2;                     // my group's row this step
        if (pr >= loC && pr <= hiC) {
            const _Float16* rc = rin + ((pr & 3) << 12);
            // wave-uniform boundary pointer selects (scalar, ~free)
            const _Float16* ruE = (pr > 0)  ? rin + (((pr - 1) & 3) << 12) : zbuf;
            const _Float16* rdE = (pr < 63) ? rin + (((pr + 1) & 3) << 12) : zbuf;
            _Float16 hinv = (_Float16)(1.0f / (float)((pr > 0) + (pr < 63) + cl + cr));

            f32x4 acc[4];
            #pragma unroll
            for (int ft = 0; ft < 4; ++ft) acc[ft] = (f32x4){0.f, 0.f, 0.f, 0.f};

            // phase 1: Ws^T @ self^T
            __builtin_amdgcn_s_setprio(1);
            #pragma unroll
            for (int ks = 0; ks < 2; ++ks) {
                int sl = ((ks * 4 + kgrp) ^ cs) << 3;
                f16x8 a = *(const f16x8*)(rc + colo + sl);
                #pragma unroll
                for (int ft = 0; ft < 4; ++ft)
                    acc[ft] = __builtin_amdgcn_mfma_f32_16x16x32_f16(wsf[ks][ft], a, acc[ft], 0, 0, 0);
            }

            // phase 2: Wn^T @ agg^T (zero-slot boundary reads)
            #pragma unroll
            for (int ks = 0; ks < 2; ++ks) {
                int c8 = ks * 4 + kgrp;
                int sl = (c8 ^ cs) << 3;
                f16x8 u = *(const f16x8*)(ruE + colo + sl);
                f16x8 d = *(const f16x8*)(rdE + colo + sl);
                // per-lane address select: edge lanes read the zero slot
                const _Float16* lp = cl ? (rc + cmo + ((c8 ^ ((col - 1) & 7)) << 3)) : zbuf;
                const _Float16* rp = cr ? (rc + cpo + ((c8 ^ ((col + 1) & 7)) << 3)) : zbuf;
                f16x8 lv = *(const f16x8*)lp;
                f16x8 rv = *(const f16x8*)rp;
                f16x8 sm = (lv + rv) + (u + d);
                f16x8 g;
                #pragma unroll
                for (int e = 0; e < 8; ++e) g[e] = sm[e] * hinv;
                #pragma unroll
                for (int ft = 0; ft < 4; ++ft)
                    acc[ft] = __builtin_amdgcn_mfma_f32_16x16x32_f16(wnf[ks][ft], g, acc[ft], 0, 0, 0);
            }
            __builtin_amdgcn_s_setprio(0);

            // epilogue: +bias, LN, residual+ReLU -> ring or logits
            float s1 = 0.f, s2 = 0.f;
            #pragma unroll
            for (int ft = 0; ft < 4; ++ft) {
                acc[ft] += cbq[ft];
                #pragma unroll
                for (int t = 0; t < 4; ++t) { float xv = acc[ft][t]; s1 += xv; s2 += xv * xv; }
            }
            s1 += __shfl_xor(s1, 16); s1 += __shfl_xor(s1, 32);
            s2 += __shfl_xor(s2, 16); s2 += __shfl_xor(s2, 32);
            float mu   = s1 * (1.0f / H);
            float var  = s2 * (1.0f / H) - mu * mu;
            float rstd = rsqrtf(var + LN_EPS);

            const _Float16* res = rc + colo;
            if (grp < 2) {
                _Float16* outp = rout + ((pr & 3) << 12) + colo;
                #pragma unroll
                for (int ft = 0; ft < 4; ++ft) {
                    f32x4 lgq = *(const f32x4*)&myp[64 + ft * 16 + kq];
                    f32x4 lbq = *(const f32x4*)&myp[128 + ft * 16 + kq];
                    int slot = (ft * 2 + (kgrp >> 1)) ^ cs;
                    f16x4 rq = *(const f16x4*)(res + (slot << 3) + (kgrp & 1) * 4);
                    f16x4 oq;
                    #pragma unroll
                    for (int t = 0; t < 4; ++t) {
                        float o = (float)rq[t]
                                + fmaxf((acc[ft][t] - mu) * rstd * lgq[t] + lbq[t], 0.f);
                        oq[t] = (_Float16)o;
                    }
                    *(f16x4*)(outp + (slot << 3) + (kgrp & 1) * 4) = oq;
                }
            } else {
                float part = 0.f;
                #pragma unroll
                for (int ft = 0; ft < 4; ++ft) {
                    f32x4 lgq = *(const f32x4*)&myp[64 + ft * 16 + kq];
                    f32x4 lbq = *(const f32x4*)&myp[128 + ft * 16 + kq];
                    f32x4 whq = *(const f32x4*)&pl[576 + ft * 16 + kq];
                    int slot = (ft * 2 + (kgrp >> 1)) ^ cs;
                    f16x4 rq = *(const f16x4*)(res + (slot << 3) + (kgrp & 1) * 4);
                    #pragma unroll
                    for (int t = 0; t < 4; ++t) {
                        float o = (float)rq[t]
                                + fmaxf((acc[ft][t] - mu) * rstd * lgq[t] + lbq[t], 0.f);
                        part += o * whq[t];
                    }
                }
                part += __shfl_xor(part, 16);
                part += __shfl_xor(part, 32);
                if (kgrp == 0)
                    logits[(size_t)img * NN + pr * GRID_D + col] = part + bh;
            }
        }
        __syncthreads();   // lands stage (vmcnt drain) + publishes ring writes
    }
}

// ---------------------------------------------------------------------------
extern "C" void kernel_launch(void* const* d_in, const int* in_sizes, int n_in,
                              void* d_out, int out_size, void* d_ws, size_t ws_size,
                              hipStream_t stream) {
    const float* x      = (const float*)d_in[0];
    // d_in[1] edge_index: fixed grid 4-neighborhood -> computed as stencil, unused
    const float* w_in   = (const float*)d_in[2];
    const float* b_in   = (const float*)d_in[3];
    const float* w_self = (const float*)d_in[4];
    const float* w_neigh= (const float*)d_in[5];
    const float* conv_b = (const float*)d_in[6];
    const float* ln_g   = (const float*)d_in[7];
    const float* ln_b   = (const float*)d_in[8];
    const float* w_head = (const float*)d_in[9];
    const float* b_head = (const float*)d_in[10];
    float* out = (float*)d_out;

    char* base = (char*)d_ws;
    const size_t HBYTES = (size_t)B_SZ * NN * H * sizeof(_Float16);   // 64 MiB
    _Float16* h_a = (_Float16*)base;
    _Float16* wtb = (_Float16*)(base + HBYTES);                       // 48 KiB

    k_inproj<<<B_SZ * GRID_D, 256, 0, stream>>>(
        x, w_in, b_in, h_a, w_self, w_neigh, wtb);
    k_fused<<<B_SZ * 2, 768, 0, stream>>>(
        h_a, out, wtb, conv_b, ln_g, ln_b, w_head, b_head);
}